// Round 1
// 251.980 us; speedup vs baseline: 1.0286x; 1.0286x over previous
//
#include <hip/hip_runtime.h>
#include <hip/hip_fp16.h>

#define N_NODES 50000
#define N_EDGES 600000
#define N_GRAPHS 64
#define HID 128
#define OUT_C 32

#define N_SCAN_BLOCKS ((N_NODES + 255) / 256)   // 196
#define SCAN_FLAG 0x40000000

typedef __attribute__((ext_vector_type(8))) _Float16 half8;
typedef __attribute__((ext_vector_type(4))) float f32x4;

// zero region layout (contiguous ints): degi[50000] cursor[50000] bsum[196]
#define ZERO_INTS (2 * N_NODES + N_SCAN_BLOCKS)

// ================= zero counters (tiny, ahead of CSR chain) =================
__global__ __launch_bounds__(256) void zero_kernel(int* __restrict__ zb) {
    int i = blockIdx.x * 256 + threadIdx.x;
    if (i < ZERO_INTS) zb[i] = 0;
}

// ================= degrees + graph boundaries + weight casts (independent, ride along) =================
#define DEG_BLOCKS ((N_EDGES + 255) / 256)       // 2344
#define GST_BLOCKS ((N_NODES + 256) / 256)       // 196 (covers 0..N_NODES)

__global__ __launch_bounds__(256) void deg_gst_w(
    const int* __restrict__ dst, int* __restrict__ degi,
    const int* __restrict__ batch, int* __restrict__ gstart,
    const float* __restrict__ W1l, const float* __restrict__ W1r,
    const float* __restrict__ W2l, const float* __restrict__ W2r,
    __half* __restrict__ Wt1, __half* __restrict__ Wt2) {
    const int b = blockIdx.x;
    const int t = threadIdx.x;
    if (b < DEG_BLOCKS) {
        int e = b * 256 + t;
        if (e < N_EDGES) atomicAdd(&degi[dst[e]], 1);
    } else if (b < DEG_BLOCKS + GST_BLOCKS) {
        int i = (b - DEG_BLOCKS) * 256 + t;
        if (i <= N_NODES) {
            if (i == 0) {
                int b1 = batch[0];
                for (int g = 0; g <= b1; ++g) gstart[g] = 0;
            } else if (i == N_NODES) {
                int b0 = batch[N_NODES - 1];
                for (int g = b0 + 1; g <= N_GRAPHS; ++g) gstart[g] = N_NODES;
            } else {
                int b0 = batch[i - 1], b1 = batch[i];
                for (int g = b0 + 1; g <= b1; ++g) gstart[g] = i;
            }
        }
    } else {
        int local = (b - DEG_BLOCKS - GST_BLOCKS) * 256 + t;
        for (int i = local; i < 65536; i += 4096) {
            int which = i >> 15;                    // 0: layer1, 1: layer2
            int j = i & 32767;
            int n = j >> 8, k = j & 255;
            const float* Wl = which ? W2l : W1l;
            const float* Wr = which ? W2r : W1r;
            float a = (k < 128) ? Wl[n * 128 + k] : Wr[n * 128 + (k - 128)];
            (which ? Wt2 : Wt1)[j] = __float2half(a);
        }
    }
}

// ================= CSR: single-dispatch scan (decoupled lookback) =================
__global__ __launch_bounds__(256) void scan_fused(
    const int* __restrict__ deg, int* __restrict__ bsum,
    int* __restrict__ rowptr, float* __restrict__ invdeg) {
    __shared__ int s[256];
    const int b = blockIdx.x;
    const int t = threadIdx.x;
    const int idx = b * 256 + t;
    const int v = (idx < N_NODES) ? deg[idx] : 0;
    s[t] = v;
    __syncthreads();
    for (int off = 1; off < 256; off <<= 1) {
        int u = (t >= off) ? s[t - off] : 0;
        __syncthreads();
        s[t] += u;
        __syncthreads();
    }
    const int incl = s[t];
    if (t == 255) atomicExch(&bsum[b], incl | SCAN_FLAG);

    int pv = 0;
    if (t < b) {
        int w;
        do { w = atomicAdd(&bsum[t], 0); } while (!(w & SCAN_FLAG));
        pv = w & ~SCAN_FLAG;
    }
    __syncthreads();
    s[t] = pv;
    __syncthreads();
    for (int off = 128; off > 0; off >>= 1) {
        if (t < off) s[t] += s[t + off];
        __syncthreads();
    }
    const int boffs = s[0];

    if (idx < N_NODES) {
        rowptr[idx] = boffs + incl - v;
        invdeg[idx] = 1.0f / fmaxf((float)v, 1.0f);
    }
    if (b == N_SCAN_BLOCKS - 1 && t == 255) rowptr[N_NODES] = boffs + incl;
}

// ================= CSR fill + x->fp16 cast (independent, ride along) =================
__global__ __launch_bounds__(256) void fill_cast(
    const int* __restrict__ src, const int* __restrict__ dst,
    const int* __restrict__ rowptr, int* __restrict__ cursor,
    int* __restrict__ eidx,
    const float* __restrict__ x, __half* __restrict__ xh) {
    const int b = blockIdx.x;
    const int t = threadIdx.x;
    if (b < DEG_BLOCKS) {
        int e = b * 256 + t;
        if (e < N_EDGES) {
            int d = dst[e];
            int pos = atomicAdd(&cursor[d], 1);
            eidx[rowptr[d] + pos] = src[e];
        }
    } else {
        int i = ((b - DEG_BLOCKS) * 256 + t) * 4;
        if (i < N_NODES * 128) {
            float4 v = *(const float4*)(x + i);
            __half2 a = __floats2half2_rn(v.x, v.y);
            __half2 c = __floats2half2_rn(v.z, v.w);
            uint2 st;
            st.x = *(const unsigned int*)&a;
            st.y = *(const unsigned int*)&c;
            *(uint2*)(xh + i) = st;
        }
    }
}

// ================= fp16 gather-aggregate: index-prefetch + 16-deep single-round chunks =================
__global__ __launch_bounds__(256) void aggregate_f16(
    const __half* __restrict__ feat16, const int* __restrict__ rowptr,
    const int* __restrict__ eidx, const float* __restrict__ invdeg,
    __half* __restrict__ mean16) {
    const int tid  = threadIdx.x;
    const int lane = tid & 63;
    const int sub  = lane & 15;
    const int gbase = lane & 48;               // 16-lane group base within wave
    const int node = blockIdx.x * 16 + (tid >> 4);
    const bool act = (node < N_NODES);
    int beg = 0, end = 0;
    if (act) { beg = rowptr[node]; end = rowptr[node + 1]; }
    const int deg = end - beg;
    const size_t coff = (size_t)sub * 8;

    // one-round index prefetch: covers degrees up to 32 with NO dependent eidx loads later
    int pre0 = 0, pre1 = 0;
    if (deg > 0) {
        pre0 = eidx[min(beg + sub,      end - 1)];
        pre1 = eidx[min(beg + 16 + sub, end - 1)];
    }

    float4 a[4], bb[4];
#pragma unroll
    for (int g = 0; g < 4; ++g) { a[g] = (float4){0.f,0.f,0.f,0.f}; bb[g] = (float4){0.f,0.f,0.f,0.f}; }

    for (int j0 = 0; j0 < deg; j0 += 16) {
        int idx[16];
        if (j0 == 0) {
#pragma unroll
            for (int k = 0; k < 16; ++k) idx[k] = __shfl(pre0, gbase + k);
        } else if (j0 == 16) {
#pragma unroll
            for (int k = 0; k < 16; ++k) idx[k] = __shfl(pre1, gbase + k);
        } else {
            // degree > 32: astronomically rare (Poisson λ=12); correctness path
#pragma unroll
            for (int k = 0; k < 16; ++k) idx[k] = eidx[min(beg + j0 + k, end - 1)];
        }
        half8 v[16];
#pragma unroll
        for (int k = 0; k < 16; ++k)
            v[k] = *(const half8*)(feat16 + (size_t)idx[k] * 128 + coff);
        const int rem = deg - j0;
#pragma unroll
        for (int k = 0; k < 16; ++k) {
            const float w = (k < rem) ? 1.0f : 0.0f;
            const int g = k & 3;
            a[g].x  += w * (float)v[k][0];
            a[g].y  += w * (float)v[k][1];
            a[g].z  += w * (float)v[k][2];
            a[g].w  += w * (float)v[k][3];
            bb[g].x += w * (float)v[k][4];
            bb[g].y += w * (float)v[k][5];
            bb[g].z += w * (float)v[k][6];
            bb[g].w += w * (float)v[k][7];
        }
    }

    if (act) {
        const float sc = invdeg[node];
        half8 r;
        r[0] = (_Float16)(((a[0].x + a[1].x) + (a[2].x + a[3].x)) * sc);
        r[1] = (_Float16)(((a[0].y + a[1].y) + (a[2].y + a[3].y)) * sc);
        r[2] = (_Float16)(((a[0].z + a[1].z) + (a[2].z + a[3].z)) * sc);
        r[3] = (_Float16)(((a[0].w + a[1].w) + (a[2].w + a[3].w)) * sc);
        r[4] = (_Float16)(((bb[0].x + bb[1].x) + (bb[2].x + bb[3].x)) * sc);
        r[5] = (_Float16)(((bb[0].y + bb[1].y) + (bb[2].y + bb[3].y)) * sc);
        r[6] = (_Float16)(((bb[0].z + bb[1].z) + (bb[2].z + bb[3].z)) * sc);
        r[7] = (_Float16)(((bb[0].w + bb[1].w) + (bb[2].w + bb[3].w)) * sc);
        *(half8*)(mean16 + (size_t)node * 128 + coff) = r;
    }
}

// ================= fp16 MFMA SAGE GEMM (M=50000, N=128, K=256) =================
#define GBM 64
#define BPAD 8

__global__ __launch_bounds__(256) void sage_gemm_f16(
    const __half* __restrict__ mean16, const __half* __restrict__ feat16,
    const __half* __restrict__ Wt, const float* __restrict__ bias,
    __half* __restrict__ out16, int M) {
    __shared__ __align__(16) __half Bs[128][256 + BPAD];

    const int tid = threadIdx.x;
    const int wave = tid >> 6;
    const int lane = tid & 63;
    const int l15 = lane & 15;
    const int quad = lane >> 4;
    const int row0 = blockIdx.x * GBM;
    const int gi_a = min(row0 + wave * 16 + l15, M - 1);

    for (int id = tid; id < 128 * 32; id += 256) {
        int n = id >> 5;
        int kc = (id & 31) * 8;
        *(half8*)&Bs[n][kc] = *(const half8*)(Wt + (size_t)n * 256 + kc);
    }

    half8 af[8];
#pragma unroll
    for (int kb = 0; kb < 8; ++kb) {
        const int k0 = kb * 32;
        const __half* ap = (k0 < 128)
            ? (mean16 + (size_t)gi_a * 128 + k0 + quad * 8)
            : (feat16 + (size_t)gi_a * 128 + (k0 - 128) + quad * 8);
        af[kb] = *(const half8*)ap;
    }

    f32x4 acc[8];
#pragma unroll
    for (int t = 0; t < 8; ++t) acc[t] = (f32x4){0.f, 0.f, 0.f, 0.f};

    __syncthreads();

#pragma unroll
    for (int kb = 0; kb < 8; ++kb) {
#pragma unroll
        for (int t = 0; t < 8; ++t) {
            const half8 b = *(const half8*)&Bs[t * 16 + l15][kb * 32 + quad * 8];
            acc[t] = __builtin_amdgcn_mfma_f32_16x16x32_f16(af[kb], b, acc[t], 0, 0, 0);
        }
    }

#pragma unroll
    for (int r = 0; r < 4; ++r) {
        int gi = row0 + wave * 16 + quad * 4 + r;
        if (gi < M) {
#pragma unroll
            for (int t = 0; t < 8; ++t) {
                int col = t * 16 + l15;
                float v = fmaxf(acc[t][r] + bias[col], 0.f);
                out16[(size_t)gi * 128 + col] = __float2half(v);
            }
        }
    }
}

// ================= pooling: per-part partial sums, boundaries from gstart =================
#define POOL_PARTS 4
__global__ __launch_bounds__(256) void pool_parts(
    const __half* __restrict__ h, const int* __restrict__ gstart,
    float* __restrict__ pooled_parts) {
    const int g = blockIdx.x >> 2;
    const int part = blockIdx.x & 3;
    const int start = gstart[g];
    const int end = gstart[g + 1];

    const int t = threadIdx.x;
    const int c4 = (t & 31) * 4;
    const int rg = t >> 5;
    float4 acc = {0.f, 0.f, 0.f, 0.f};
    for (int n = start + part * 8 + rg; n < end; n += 8 * POOL_PARTS) {
        const __half2* p = (const __half2*)(h + (size_t)n * 128 + c4);
        float2 f0 = __half22float2(p[0]);
        float2 f1 = __half22float2(p[1]);
        acc.x += f0.x; acc.y += f0.y; acc.z += f1.x; acc.w += f1.y;
    }
    __shared__ float sm[8][132];
    sm[rg][c4 + 0] = acc.x;
    sm[rg][c4 + 1] = acc.y;
    sm[rg][c4 + 2] = acc.z;
    sm[rg][c4 + 3] = acc.w;
    __syncthreads();
    if (t < 128) {
        float s = 0.f;
#pragma unroll
        for (int r = 0; r < 8; ++r) s += sm[r][t];
        pooled_parts[(size_t)blockIdx.x * 128 + t] = s;
    }
}

// ================= final linear (parts summed inline) =================
__global__ void final_kernel(const float* __restrict__ pooled_parts,
                             const int* __restrict__ gstart,
                             const float* __restrict__ Wlin, const float* __restrict__ blin,
                             float* __restrict__ out) {
    int g = blockIdx.x;
    int j = threadIdx.x;               // 0..31
    float inv = 1.0f / fmaxf((float)(gstart[g + 1] - gstart[g]), 1.0f);
    float sum = blin[j];
    const float* w = Wlin + j * 128;
    const float* p0 = pooled_parts + (size_t)(g * 4 + 0) * 128;
    const float* p1 = pooled_parts + (size_t)(g * 4 + 1) * 128;
    const float* p2 = pooled_parts + (size_t)(g * 4 + 2) * 128;
    const float* p3 = pooled_parts + (size_t)(g * 4 + 3) * 128;
    for (int c = 0; c < 128; ++c) {
        float p = (p0[c] + p1[c]) + (p2[c] + p3[c]);
        sum += p * inv * w[c];
    }
    out[g * 32 + j] = sum;
}

extern "C" void kernel_launch(void* const* d_in, const int* in_sizes, int n_in,
                              void* d_out, int out_size, void* d_ws, size_t ws_size,
                              hipStream_t stream) {
    const float* x    = (const float*)d_in[0];
    const int*   src  = (const int*)d_in[1];
    const int*   dst  = ((const int*)d_in[1]) + N_EDGES;
    const int*   batch= (const int*)d_in[2];
    const float* W1l  = (const float*)d_in[3];
    const float* b1   = (const float*)d_in[4];
    const float* W1r  = (const float*)d_in[5];
    const float* W2l  = (const float*)d_in[6];
    const float* b2   = (const float*)d_in[7];
    const float* W2r  = (const float*)d_in[8];
    const float* Wlin = (const float*)d_in[9];
    const float* blin = (const float*)d_in[10];
    float* out = (float*)d_out;

    __half* xh     = (__half*)d_ws;                 // 6,400,000 h
    __half* mean16 = xh + 6400000;                  // 6,400,000 h
    __half* h1_16  = mean16 + 6400000;              // 6,400,000 h
    __half* h2_16  = h1_16 + 6400000;               // 6,400,000 h
    __half* Wt1    = h2_16 + 6400000;               // 32,768 h
    __half* Wt2    = Wt1 + 32768;                   // 32,768 h
    float* pooled_parts = (float*)(Wt2 + 32768);    // 32,768 f
    float* invdeg  = pooled_parts + 32768;          // 50,000 f
    int*   gstart  = (int*)(invdeg + N_NODES);      // 65 i
    // contiguous zero region: degi, cursor, bsum
    int*   degi    = gstart + 65;                   // 50,000 i
    int*   cursor  = degi + N_NODES;                // 50,000 i
    int*   bsum    = cursor + N_NODES;              // 196 i
    int*   rowptr  = bsum + N_SCAN_BLOCKS;          // 50,001 i
    int*   eidx    = rowptr + N_NODES + 1;          // 600,000 i

    // 1) zero counters (tiny)
    zero_kernel<<<(ZERO_INTS + 255) / 256, 256, 0, stream>>>(degi);

    // 2) degrees + graph boundaries + weight casts (ride-along)
    deg_gst_w<<<DEG_BLOCKS + GST_BLOCKS + 16, 256, 0, stream>>>(
        dst, degi, batch, gstart, W1l, W1r, W2l, W2r, Wt1, Wt2);

    // 3) fused lookback scan
    scan_fused<<<N_SCAN_BLOCKS, 256, 0, stream>>>(degi, bsum, rowptr, invdeg);

    // 4) CSR fill + x->fp16 cast (ride-along; cast completes right before agg1 needs it)
    fill_cast<<<DEG_BLOCKS + (N_NODES * 128 / 4 + 255) / 256, 256, 0, stream>>>(
        src, dst, rowptr, cursor, eidx, x, xh);

    const int gemm_grid = (N_NODES + GBM - 1) / GBM;   // 782
    const int agg_grid = (N_NODES + 15) / 16;          // 3125

    // 5-6) layer 1
    aggregate_f16<<<agg_grid, 256, 0, stream>>>(xh, rowptr, eidx, invdeg, mean16);
    sage_gemm_f16<<<gemm_grid, 256, 0, stream>>>(mean16, xh, Wt1, b1, h1_16, N_NODES);

    // 7-8) layer 2
    aggregate_f16<<<agg_grid, 256, 0, stream>>>(h1_16, rowptr, eidx, invdeg, mean16);
    sage_gemm_f16<<<gemm_grid, 256, 0, stream>>>(mean16, h1_16, Wt2, b2, h2_16, N_NODES);

    // 9-10) pool partials + final linear
    pool_parts<<<N_GRAPHS * POOL_PARTS, 256, 0, stream>>>(h2_16, gstart, pooled_parts);
    final_kernel<<<N_GRAPHS, 32, 0, stream>>>(pooled_parts, gstart, Wlin, blin, out);
}

// Round 2
// 250.517 us; speedup vs baseline: 1.0346x; 1.0058x over previous
//
#include <hip/hip_runtime.h>
#include <hip/hip_fp16.h>

#define N_NODES 50000
#define N_EDGES 600000
#define N_GRAPHS 64
#define HID 128
#define OUT_C 32

#define N_SCAN_BLOCKS ((N_NODES + 255) / 256)   // 196
#define SCAN_FLAG 0x40000000

typedef __attribute__((ext_vector_type(8))) _Float16 half8;
typedef __attribute__((ext_vector_type(4))) float f32x4;

// zero region layout (contiguous ints): degi[50000] cursor[50000] bsum[196] pooled[8192]
#define ZERO_INTS (2 * N_NODES + N_SCAN_BLOCKS + N_GRAPHS * HID)

// ================= zero counters + pooled accum =================
__global__ __launch_bounds__(256) void zero_kernel(int* __restrict__ zb) {
    int i = blockIdx.x * 256 + threadIdx.x;
    if (i < ZERO_INTS) zb[i] = 0;
}

// ================= degrees + graph boundaries + weight casts (ride along) =================
#define DEG_BLOCKS ((N_EDGES + 255) / 256)       // 2344
#define GST_BLOCKS ((N_NODES + 256) / 256)       // 196

__global__ __launch_bounds__(256) void deg_gst_w(
    const int* __restrict__ dst, int* __restrict__ degi,
    const int* __restrict__ batch, int* __restrict__ gstart,
    const float* __restrict__ W1l, const float* __restrict__ W1r,
    const float* __restrict__ W2l, const float* __restrict__ W2r,
    __half* __restrict__ Wt1, __half* __restrict__ Wt2) {
    const int b = blockIdx.x;
    const int t = threadIdx.x;
    if (b < DEG_BLOCKS) {
        int e = b * 256 + t;
        if (e < N_EDGES) atomicAdd(&degi[dst[e]], 1);
    } else if (b < DEG_BLOCKS + GST_BLOCKS) {
        int i = (b - DEG_BLOCKS) * 256 + t;
        if (i <= N_NODES) {
            if (i == 0) {
                int b1 = batch[0];
                for (int g = 0; g <= b1; ++g) gstart[g] = 0;
            } else if (i == N_NODES) {
                int b0 = batch[N_NODES - 1];
                for (int g = b0 + 1; g <= N_GRAPHS; ++g) gstart[g] = N_NODES;
            } else {
                int b0 = batch[i - 1], b1 = batch[i];
                for (int g = b0 + 1; g <= b1; ++g) gstart[g] = i;
            }
        }
    } else {
        int local = (b - DEG_BLOCKS - GST_BLOCKS) * 256 + t;
        for (int i = local; i < 65536; i += 4096) {
            int which = i >> 15;
            int j = i & 32767;
            int n = j >> 8, k = j & 255;
            const float* Wl = which ? W2l : W1l;
            const float* Wr = which ? W2r : W1r;
            float a = (k < 128) ? Wl[n * 128 + k] : Wr[n * 128 + (k - 128)];
            (which ? Wt2 : Wt1)[j] = __float2half(a);
        }
    }
}

// ================= CSR: single-dispatch scan (decoupled lookback) =================
__global__ __launch_bounds__(256) void scan_fused(
    const int* __restrict__ deg, int* __restrict__ bsum,
    int* __restrict__ rowptr, float* __restrict__ invdeg) {
    __shared__ int s[256];
    const int b = blockIdx.x;
    const int t = threadIdx.x;
    const int idx = b * 256 + t;
    const int v = (idx < N_NODES) ? deg[idx] : 0;
    s[t] = v;
    __syncthreads();
    for (int off = 1; off < 256; off <<= 1) {
        int u = (t >= off) ? s[t - off] : 0;
        __syncthreads();
        s[t] += u;
        __syncthreads();
    }
    const int incl = s[t];
    if (t == 255) atomicExch(&bsum[b], incl | SCAN_FLAG);

    int pv = 0;
    if (t < b) {
        int w;
        do { w = atomicAdd(&bsum[t], 0); } while (!(w & SCAN_FLAG));
        pv = w & ~SCAN_FLAG;
    }
    __syncthreads();
    s[t] = pv;
    __syncthreads();
    for (int off = 128; off > 0; off >>= 1) {
        if (t < off) s[t] += s[t + off];
        __syncthreads();
    }
    const int boffs = s[0];

    if (idx < N_NODES) {
        rowptr[idx] = boffs + incl - v;
        invdeg[idx] = 1.0f / fmaxf((float)v, 1.0f);
    }
    if (b == N_SCAN_BLOCKS - 1 && t == 255) rowptr[N_NODES] = boffs + incl;
}

// ================= CSR fill + x->fp16 cast (ride along) =================
__global__ __launch_bounds__(256) void fill_cast(
    const int* __restrict__ src, const int* __restrict__ dst,
    const int* __restrict__ rowptr, int* __restrict__ cursor,
    int* __restrict__ eidx,
    const float* __restrict__ x, __half* __restrict__ xh) {
    const int b = blockIdx.x;
    const int t = threadIdx.x;
    if (b < DEG_BLOCKS) {
        int e = b * 256 + t;
        if (e < N_EDGES) {
            int d = dst[e];
            int pos = atomicAdd(&cursor[d], 1);
            eidx[rowptr[d] + pos] = src[e];
        }
    } else {
        int i = ((b - DEG_BLOCKS) * 256 + t) * 4;
        if (i < N_NODES * 128) {
            float4 v = *(const float4*)(x + i);
            __half2 a = __floats2half2_rn(v.x, v.y);
            __half2 c = __floats2half2_rn(v.z, v.w);
            uint2 st;
            st.x = *(const unsigned int*)&a;
            st.y = *(const unsigned int*)&c;
            *(uint2*)(xh + i) = st;
        }
    }
}

// ================= fused: aggregate(64 nodes) -> MFMA GEMM -> (relu store | pool) ======
// LDS: Bs 64KB + Ms 16KB = 80KB exactly -> 2 blocks/CU.
// Swizzle (both sides): byte_off ^= (row&7)<<4 within each row.
#define GBM 64

__global__ __launch_bounds__(256, 2) void sage_fused(
    const __half* __restrict__ feat16, const int* __restrict__ rowptr,
    const int* __restrict__ eidx, const float* __restrict__ invdeg,
    const __half* __restrict__ Wt, const float* __restrict__ bias,
    __half* __restrict__ out16,
    const int* __restrict__ batch, float* __restrict__ pooled,
    int M, int do_pool) {
    __shared__ __align__(16) __half Bs[128 * 256];   // weights, swizzled rows (512B)
    __shared__ __align__(16) __half Ms[64 * 128];    // mean tile, swizzled rows (256B)

    const int tid = threadIdx.x;
    const int wave = tid >> 6;
    const int lane = tid & 63;
    const int l15 = lane & 15;
    const int quad = lane >> 4;
    const int row0 = blockIdx.x * GBM;

    // ---- stage B into LDS (swizzled) ----
    for (int id = tid; id < 128 * 32; id += 256) {
        int n = id >> 5;
        int kc16 = (id & 31) * 16;                       // byte col within row
        int off = (n * 512 + kc16) ^ ((n & 7) << 4);
        *(half8*)((char*)Bs + off) = *(const half8*)((const char*)Wt + n * 512 + kc16);
    }

    // ---- aggregate: 16 groups x 4 nodes each into Ms ----
    const int g16 = tid >> 4;          // 0..15
    const int sub = tid & 15;
    const int gbase = lane & 48;
    const size_t coff = (size_t)sub * 8;   // halves

    int begq[4], endq[4], pre0q[4], pre1q[4];
#pragma unroll
    for (int q = 0; q < 4; ++q) {
        int node = row0 + g16 + 16 * q;
        int bq = 0, eq = 0;
        if (node < M) { bq = rowptr[node]; eq = rowptr[node + 1]; }
        begq[q] = bq; endq[q] = eq;
    }
#pragma unroll
    for (int q = 0; q < 4; ++q) {
        int bq = begq[q], eq = endq[q];
        pre0q[q] = (eq > bq) ? eidx[min(bq + sub,      eq - 1)] : 0;
        pre1q[q] = (eq > bq) ? eidx[min(bq + 16 + sub, eq - 1)] : 0;
    }

#pragma unroll
    for (int q = 0; q < 4; ++q) {
        const int nloc = g16 + 16 * q;
        const int node = row0 + nloc;
        const int beg = begq[q], end = endq[q];
        const int deg = end - beg;

        float4 a[4], bb[4];
#pragma unroll
        for (int g = 0; g < 4; ++g) { a[g] = (float4){0.f,0.f,0.f,0.f}; bb[g] = (float4){0.f,0.f,0.f,0.f}; }

        for (int j0 = 0; j0 < deg; j0 += 16) {
            int idx[16];
            if (j0 == 0) {
#pragma unroll
                for (int k = 0; k < 16; ++k) idx[k] = __shfl(pre0q[q], gbase + k);
            } else if (j0 == 16) {
#pragma unroll
                for (int k = 0; k < 16; ++k) idx[k] = __shfl(pre1q[q], gbase + k);
            } else {
#pragma unroll
                for (int k = 0; k < 16; ++k) idx[k] = eidx[min(beg + j0 + k, end - 1)];
            }
            half8 v[16];
#pragma unroll
            for (int k = 0; k < 16; ++k)
                v[k] = *(const half8*)(feat16 + (size_t)idx[k] * 128 + coff);
            const int rem = deg - j0;
#pragma unroll
            for (int k = 0; k < 16; ++k) {
                const float w = (k < rem) ? 1.0f : 0.0f;
                const int g = k & 3;
                a[g].x  += w * (float)v[k][0];
                a[g].y  += w * (float)v[k][1];
                a[g].z  += w * (float)v[k][2];
                a[g].w  += w * (float)v[k][3];
                bb[g].x += w * (float)v[k][4];
                bb[g].y += w * (float)v[k][5];
                bb[g].z += w * (float)v[k][6];
                bb[g].w += w * (float)v[k][7];
            }
        }

        const float sc = (node < M) ? invdeg[node] : 1.0f;
        half8 r;
        r[0] = (_Float16)(((a[0].x + a[1].x) + (a[2].x + a[3].x)) * sc);
        r[1] = (_Float16)(((a[0].y + a[1].y) + (a[2].y + a[3].y)) * sc);
        r[2] = (_Float16)(((a[0].z + a[1].z) + (a[2].z + a[3].z)) * sc);
        r[3] = (_Float16)(((a[0].w + a[1].w) + (a[2].w + a[3].w)) * sc);
        r[4] = (_Float16)(((bb[0].x + bb[1].x) + (bb[2].x + bb[3].x)) * sc);
        r[5] = (_Float16)(((bb[0].y + bb[1].y) + (bb[2].y + bb[3].y)) * sc);
        r[6] = (_Float16)(((bb[0].z + bb[1].z) + (bb[2].z + bb[3].z)) * sc);
        r[7] = (_Float16)(((bb[0].w + bb[1].w) + (bb[2].w + bb[3].w)) * sc);
        int moff = (nloc * 256 + (int)sub * 16) ^ ((nloc & 7) << 4);
        *(half8*)((char*)Ms + moff) = r;
    }

    __syncthreads();

    // ---- GEMM: A = [Ms | feat16], B = Bs ----
    const int arow = wave * 16 + l15;
    const int gi_a = min(row0 + arow, M - 1);
    half8 af[8];
#pragma unroll
    for (int kb = 0; kb < 4; ++kb) {
        int off = (arow * 256 + kb * 64 + quad * 16) ^ ((arow & 7) << 4);
        af[kb] = *(const half8*)((const char*)Ms + off);
    }
#pragma unroll
    for (int kb = 4; kb < 8; ++kb) {
        af[kb] = *(const half8*)(feat16 + (size_t)gi_a * 128 + (kb - 4) * 32 + quad * 8);
    }

    f32x4 acc[8];
#pragma unroll
    for (int t = 0; t < 8; ++t) acc[t] = (f32x4){0.f, 0.f, 0.f, 0.f};

#pragma unroll
    for (int kb = 0; kb < 8; ++kb) {
#pragma unroll
        for (int t = 0; t < 8; ++t) {
            const int n = t * 16 + l15;
            const int boff = (n * 512 + kb * 64 + quad * 16) ^ ((n & 7) << 4);
            const half8 b = *(const half8*)((const char*)Bs + boff);
            acc[t] = __builtin_amdgcn_mfma_f32_16x16x32_f16(af[kb], b, acc[t], 0, 0, 0);
        }
    }

    if (!do_pool) {
        // ---- epilogue: bias + relu -> out16 ----
#pragma unroll
        for (int r = 0; r < 4; ++r) {
            int gi = row0 + wave * 16 + quad * 4 + r;
            if (gi < M) {
#pragma unroll
                for (int t = 0; t < 8; ++t) {
                    int col = t * 16 + l15;
                    float v = fmaxf(acc[t][r] + bias[col], 0.f);
                    out16[(size_t)gi * 128 + col] = __float2half(v);
                }
            }
        }
    } else {
        // ---- epilogue: bias + relu -> Ms (fp16), then pool over graph segments ----
        __syncthreads();   // all Ms(A) reads complete
#pragma unroll
        for (int r = 0; r < 4; ++r) {
            int lrow = wave * 16 + quad * 4 + r;
            int gi = row0 + lrow;
#pragma unroll
            for (int t = 0; t < 8; ++t) {
                int col = t * 16 + l15;
                float v = fmaxf(acc[t][r] + bias[col], 0.f);
                if (gi >= M) v = 0.f;
                int off = (lrow * 256 + col * 2) ^ ((lrow & 7) << 4);
                *(__half*)((char*)Ms + off) = __float2half(v);
            }
        }
        __syncthreads();
        if (tid < 128) {
            const int col = tid;
            int cur = batch[min(row0, M - 1)];
            float s = 0.f;
            for (int r = 0; r < 64; ++r) {
                int gr = batch[min(row0 + r, M - 1)];
                if (gr != cur) {
                    atomicAdd(&pooled[cur * 128 + col], s);
                    s = 0.f; cur = gr;
                }
                int off = (r * 256 + col * 2) ^ ((r & 7) << 4);
                s += __half2float(*(const __half*)((const char*)Ms + off));
            }
            atomicAdd(&pooled[cur * 128 + col], s);
        }
    }
}

// ================= final linear =================
__global__ void final_kernel(const float* __restrict__ pooled,
                             const int* __restrict__ gstart,
                             const float* __restrict__ Wlin, const float* __restrict__ blin,
                             float* __restrict__ out) {
    int g = blockIdx.x;
    int j = threadIdx.x;               // 0..31
    float inv = 1.0f / fmaxf((float)(gstart[g + 1] - gstart[g]), 1.0f);
    float sum = blin[j];
    const float* w = Wlin + j * 128;
    const float* p = pooled + (size_t)g * 128;
    for (int c = 0; c < 128; ++c) {
        sum += p[c] * inv * w[c];
    }
    out[g * 32 + j] = sum;
}

extern "C" void kernel_launch(void* const* d_in, const int* in_sizes, int n_in,
                              void* d_out, int out_size, void* d_ws, size_t ws_size,
                              hipStream_t stream) {
    const float* x    = (const float*)d_in[0];
    const int*   src  = (const int*)d_in[1];
    const int*   dst  = ((const int*)d_in[1]) + N_EDGES;
    const int*   batch= (const int*)d_in[2];
    const float* W1l  = (const float*)d_in[3];
    const float* b1   = (const float*)d_in[4];
    const float* W1r  = (const float*)d_in[5];
    const float* W2l  = (const float*)d_in[6];
    const float* b2   = (const float*)d_in[7];
    const float* W2r  = (const float*)d_in[8];
    const float* Wlin = (const float*)d_in[9];
    const float* blin = (const float*)d_in[10];
    float* out = (float*)d_out;

    __half* xh     = (__half*)d_ws;                 // 6,400,000 h
    __half* h1_16  = xh + 6400000;                  // 6,400,000 h
    __half* Wt1    = h1_16 + 6400000;               // 32,768 h
    __half* Wt2    = Wt1 + 32768;                   // 32,768 h
    float* invdeg  = (float*)(Wt2 + 32768);         // 50,000 f
    int*   gstart  = (int*)(invdeg + N_NODES);      // 65 i
    // contiguous zero region: degi, cursor, bsum, pooled
    int*   degi    = gstart + 65;                   // 50,000 i
    int*   cursor  = degi + N_NODES;                // 50,000 i
    int*   bsum    = cursor + N_NODES;              // 196 i
    float* pooled  = (float*)(bsum + N_SCAN_BLOCKS);// 8,192 f (zeroed)
    int*   rowptr  = (int*)(pooled + N_GRAPHS*HID); // 50,001 i
    int*   eidx    = rowptr + N_NODES + 1;          // 600,000 i

    // 1) zero counters + pooled accumulators
    zero_kernel<<<(ZERO_INTS + 255) / 256, 256, 0, stream>>>(degi);

    // 2) degrees + graph boundaries + weight casts
    deg_gst_w<<<DEG_BLOCKS + GST_BLOCKS + 16, 256, 0, stream>>>(
        dst, degi, batch, gstart, W1l, W1r, W2l, W2r, Wt1, Wt2);

    // 3) fused lookback scan
    scan_fused<<<N_SCAN_BLOCKS, 256, 0, stream>>>(degi, bsum, rowptr, invdeg);

    // 4) CSR fill + x->fp16 cast
    fill_cast<<<DEG_BLOCKS + (N_NODES * 128 / 4 + 255) / 256, 256, 0, stream>>>(
        src, dst, rowptr, cursor, eidx, x, xh);

    const int grid = (N_NODES + GBM - 1) / GBM;   // 782

    // 5) layer 1: agg + gemm fused
    sage_fused<<<grid, 256, 0, stream>>>(
        xh, rowptr, eidx, invdeg, Wt1, b1, h1_16, batch, pooled, N_NODES, 0);

    // 6) layer 2: agg + gemm + pool fused
    sage_fused<<<grid, 256, 0, stream>>>(
        h1_16, rowptr, eidx, invdeg, Wt2, b2, (__half*)0, batch, pooled, N_NODES, 1);

    // 7) final linear
    final_kernel<<<N_GRAPHS, 32, 0, stream>>>(pooled, gstart, Wlin, blin, out);
}